// Round 1
// baseline (244.388 us; speedup 1.0000x reference)
//
#include <hip/hip_runtime.h>

#define NN 256
#define VV 25
#define TT 128
#define CIN 64
#define CO 64
#define RR 9
#define HH4 18
#define HH5 6

__device__ __forceinline__ float silu_f(float v) {
  return v / (1.0f + __expf(-v));
}

// Kernel 1: per (n,v): x3 = x @ W3 + b3 (padded to 12), and xm = sum over t of x.
__global__ __launch_bounds__(128) void k1_proj(
    const float* __restrict__ x, const float* __restrict__ W3,
    const float* __restrict__ b3, float* __restrict__ x3p,
    float* __restrict__ xm) {
  const int blk = blockIdx.x;            // n*V + v
  const int t = threadIdx.x;             // 0..127 (one per time step)
  const float* xrow = x + ((size_t)blk * TT + t) * CIN;
  float xr[CIN];
  #pragma unroll
  for (int j = 0; j < CIN / 4; ++j) {
    float4 v4 = ((const float4*)xrow)[j];
    xr[j * 4 + 0] = v4.x; xr[j * 4 + 1] = v4.y;
    xr[j * 4 + 2] = v4.z; xr[j * 4 + 3] = v4.w;
  }
  // x3 row
  float acc[RR];
  #pragma unroll
  for (int c = 0; c < RR; ++c) acc[c] = b3[c];
  #pragma unroll
  for (int k = 0; k < CIN; ++k) {
    const float xk = xr[k];
    #pragma unroll
    for (int c = 0; c < RR; ++c) acc[c] = fmaf(xk, W3[k * RR + c], acc[c]);
  }
  float* o = x3p + ((size_t)blk * TT + t) * 12;
  ((float4*)o)[0] = make_float4(acc[0], acc[1], acc[2], acc[3]);
  ((float4*)o)[1] = make_float4(acc[4], acc[5], acc[6], acc[7]);
  ((float4*)o)[2] = make_float4(acc[8], 0.f, 0.f, 0.f);

  // xm reduction: LDS transpose, padded stride 65 (conflict-free)
  __shared__ float red[64][65];
  float csum = 0.f;
  #pragma unroll
  for (int half = 0; half < 2; ++half) {
    if ((t >> 6) == half) {
      const int tr = t & 63;
      #pragma unroll
      for (int k = 0; k < CIN; ++k) red[tr][k] = xr[k];
    }
    __syncthreads();
    if (t < CIN) {
      #pragma unroll
      for (int r = 0; r < 64; ++r) csum += red[r][t];
    }
    __syncthreads();
  }
  if (t < CIN) xm[(size_t)blk * CIN + t] = csum;
}

// Kernel 2: per n: m1/m2 (from xm), rel MLP (9->18->9), + A -> h
__global__ __launch_bounds__(128) void k2_h(
    const float* __restrict__ xm, const float* __restrict__ A,
    const float* __restrict__ W1, const float* __restrict__ b1,
    const float* __restrict__ W2, const float* __restrict__ b2,
    const float* __restrict__ W4a, const float* __restrict__ b4a,
    const float* __restrict__ W4b, const float* __restrict__ b4b,
    float* __restrict__ h) {
  const int n = blockIdx.x;
  const int tid = threadIdx.x;
  __shared__ float m1[VV][RR];
  __shared__ float m2[VV][RR];
  const float* xmn = xm + (size_t)n * VV * CIN;
  for (int i = tid; i < 2 * VV * RR; i += 128) {
    const int which = (i >= VV * RR);
    const int idx = which ? i - VV * RR : i;
    const int v = idx / RR, c = idx % RR;
    const float* W = which ? W2 : W1;
    const float* b = which ? b2 : b1;
    const float* row = xmn + v * CIN;
    float s = 0.f;
    #pragma unroll
    for (int k = 0; k < CIN; ++k) s = fmaf(row[k], W[k * RR + c], s);
    s = s * (1.0f / TT) + b[c];
    if (which) m2[v][c] = s; else m1[v][c] = s;
  }
  __syncthreads();
  for (int p = tid; p < VV * VV; p += 128) {
    const int u = p / VV, v2 = p % VV;
    float r[RR];
    #pragma unroll
    for (int c = 0; c < RR; ++c) r[c] = m1[u][c] - m2[v2][c];
    float t1[HH4];
    #pragma unroll
    for (int j = 0; j < HH4; ++j) {
      float s = b4a[j];
      #pragma unroll
      for (int c = 0; c < RR; ++c) s = fmaf(r[c], W4a[c * HH4 + j], s);
      t1[j] = silu_f(s);
    }
    const float av = A[u * VV + v2];
    float* hp = h + ((size_t)n * VV * VV + p) * RR;
    #pragma unroll
    for (int c = 0; c < RR; ++c) {
      float s = b4b[c];
      #pragma unroll
      for (int j = 0; j < HH4; ++j) s = fmaf(t1[j], W4b[j * RR + c], s);
      hp[c] = silu_f(s) + av;
    }
  }
}

// Kernel 3: per (n,u): agg over v, then 9->6->64 silu MLP, write output
__global__ __launch_bounds__(128) void k3_out(
    const float* __restrict__ x3p, const float* __restrict__ h,
    const float* __restrict__ W5a, const float* __restrict__ b5a,
    const float* __restrict__ W5b, const float* __restrict__ b5b,
    float* __restrict__ out) {
  const int blk = blockIdx.x;   // n*V + u
  const int n = blk / VV, u = blk % VV;
  const int t = threadIdx.x;
  const float* hrow = h + ((size_t)n * VV * VV + (size_t)u * VV) * RR; // uniform
  const float* xb = x3p + ((size_t)n * VV * TT + t) * 12;
  float acc[RR];
  #pragma unroll
  for (int c = 0; c < RR; ++c) acc[c] = 0.f;
  #pragma unroll
  for (int v = 0; v < VV; ++v) {
    const float* xv = xb + (size_t)v * TT * 12;
    float4 a0 = ((const float4*)xv)[0];
    float4 a1 = ((const float4*)xv)[1];
    float a8 = xv[8];
    const float* hv = hrow + v * RR;
    acc[0] = fmaf(hv[0], a0.x, acc[0]);
    acc[1] = fmaf(hv[1], a0.y, acc[1]);
    acc[2] = fmaf(hv[2], a0.z, acc[2]);
    acc[3] = fmaf(hv[3], a0.w, acc[3]);
    acc[4] = fmaf(hv[4], a1.x, acc[4]);
    acc[5] = fmaf(hv[5], a1.y, acc[5]);
    acc[6] = fmaf(hv[6], a1.z, acc[6]);
    acc[7] = fmaf(hv[7], a1.w, acc[7]);
    acc[8] = fmaf(hv[8], a8,   acc[8]);
  }
  float a5[HH5];
  #pragma unroll
  for (int j = 0; j < HH5; ++j) {
    float s = b5a[j];
    #pragma unroll
    for (int c = 0; c < RR; ++c) s = fmaf(acc[c], W5a[c * HH5 + j], s);
    a5[j] = silu_f(s);
  }
  float* orow = out + ((size_t)blk * TT + t) * CO;
  #pragma unroll
  for (int o4 = 0; o4 < CO / 4; ++o4) {
    float4 rv;
    #pragma unroll
    for (int e = 0; e < 4; ++e) {
      const int o = o4 * 4 + e;
      float s = b5b[o];
      #pragma unroll
      for (int j = 0; j < HH5; ++j) s = fmaf(a5[j], W5b[j * CO + o], s);
      (&rv.x)[e] = silu_f(s);
    }
    ((float4*)orow)[o4] = rv;
  }
}

extern "C" void kernel_launch(void* const* d_in, const int* in_sizes, int n_in,
                              void* d_out, int out_size, void* d_ws, size_t ws_size,
                              hipStream_t stream) {
  const float* x   = (const float*)d_in[0];
  const float* A   = (const float*)d_in[1];
  const float* W1  = (const float*)d_in[2];
  const float* b1  = (const float*)d_in[3];
  const float* W2  = (const float*)d_in[4];
  const float* b2  = (const float*)d_in[5];
  const float* W3  = (const float*)d_in[6];
  const float* b3  = (const float*)d_in[7];
  const float* W4a = (const float*)d_in[8];
  const float* b4a = (const float*)d_in[9];
  const float* W4b = (const float*)d_in[10];
  const float* b4b = (const float*)d_in[11];
  const float* W5a = (const float*)d_in[12];
  const float* b5a = (const float*)d_in[13];
  const float* W5b = (const float*)d_in[14];
  const float* b5b = (const float*)d_in[15];

  float* ws  = (float*)d_ws;
  float* x3p = ws;                               // 6400*128*12 = 9,830,400 floats
  float* xm  = ws + 9830400;                     // 6400*64    =   409,600 floats
  float* h   = ws + 9830400 + 409600;            // 256*625*9  = 1,440,000 floats
  float* out = (float*)d_out;

  hipLaunchKernelGGL(k1_proj, dim3(NN * VV), dim3(128), 0, stream, x, W3, b3, x3p, xm);
  hipLaunchKernelGGL(k2_h, dim3(NN), dim3(128), 0, stream,
                     xm, A, W1, b1, W2, b2, W4a, b4a, W4b, b4b, h);
  hipLaunchKernelGGL(k3_out, dim3(NN * VV), dim3(128), 0, stream,
                     x3p, h, W5a, b5a, W5b, b5b, out);
}

// Round 2
// 164.118 us; speedup vs baseline: 1.4891x; 1.4891x over previous
//
#include <hip/hip_runtime.h>
#include <hip/hip_fp16.h>

#define NN 256
#define VV 25
#define TT 128
#define CIN 64
#define CO 64
#define RR 9
#define HH4 18
#define HH5 6
#define TQ 32
#define NT (TT / TQ)

typedef unsigned int uint32;

__device__ __forceinline__ float silu_f(float v) {
  return __fdividef(v, 1.0f + __expf(-v));
}

// ---------------------------------------------------------------------------
// k1: per (n,v): stage x tile in LDS (coalesced), x3 = x@W3+b3 -> half[12],
// xm = sum_t x (column sums from LDS).
// ---------------------------------------------------------------------------
__global__ __launch_bounds__(128) void k1_proj(
    const float* __restrict__ x, const float* __restrict__ W3,
    const float* __restrict__ b3, __half* __restrict__ x3h,
    float* __restrict__ xm) {
  const int blk = blockIdx.x;  // n*V + v
  const int tid = threadIdx.x;
  __shared__ float xt[TT][65];
  __shared__ float xmp[2][64];

  const float* xs = x + (size_t)blk * TT * CIN;
  // coalesced stage: instr k reads 2 KB contiguous (128 lanes x float4)
  float4 r[16];
  #pragma unroll
  for (int k = 0; k < 16; ++k) r[k] = ((const float4*)xs)[k * 128 + tid];
  #pragma unroll
  for (int k = 0; k < 16; ++k) {
    const int idx = k * 128 + tid;       // float4 index
    const int t = idx >> 4;
    const int c = (idx & 15) * 4;
    xt[t][c + 0] = r[k].x; xt[t][c + 1] = r[k].y;
    xt[t][c + 2] = r[k].z; xt[t][c + 3] = r[k].w;
  }
  __syncthreads();

  // x3 row for t = tid (conflict-free: bank = (t + c) % 32, lanes differ in t)
  float acc[RR];
  #pragma unroll
  for (int c = 0; c < RR; ++c) acc[c] = b3[c];
  #pragma unroll 8
  for (int c = 0; c < CIN; ++c) {
    const float xv = xt[tid][c];
    #pragma unroll
    for (int j = 0; j < RR; ++j) acc[j] = fmaf(xv, W3[c * RR + j], acc[j]);
  }
  {
    union { __half h[12]; uint2 u2[3]; } row;
    #pragma unroll
    for (int j = 0; j < RR; ++j) row.h[j] = __float2half(acc[j]);
    row.h[9] = __float2half(0.f); row.h[10] = __float2half(0.f);
    row.h[11] = __float2half(0.f);
    uint2* dst = (uint2*)(x3h + ((size_t)blk * TT + tid) * 12);
    dst[0] = row.u2[0]; dst[1] = row.u2[1]; dst[2] = row.u2[2];
  }

  // xm: column sums (bank = (t + c) % 32 -> conflict-free)
  {
    const int c = tid & 63, hh = tid >> 6;
    float s = 0.f;
    #pragma unroll
    for (int j = 0; j < 64; ++j) s += xt[hh * 64 + j][c];
    xmp[hh][c] = s;
  }
  __syncthreads();
  if (tid < 64) xm[(size_t)blk * 64 + tid] = xmp[0][tid] + xmp[1][tid];
}

// ---------------------------------------------------------------------------
// k2: per n: m1/m2 from xm, rel MLP (9->18->9), + A -> h (half2 [625][5])
// ---------------------------------------------------------------------------
__global__ __launch_bounds__(128) void k2_h(
    const float* __restrict__ xm, const float* __restrict__ A,
    const float* __restrict__ W1, const float* __restrict__ b1,
    const float* __restrict__ W2, const float* __restrict__ b2,
    const float* __restrict__ W4a, const float* __restrict__ b4a,
    const float* __restrict__ W4b, const float* __restrict__ b4b,
    __half2* __restrict__ h2) {
  const int n = blockIdx.x;
  const int tid = threadIdx.x;
  __shared__ float m1[VV][RR];
  __shared__ float m2[VV][RR];
  const float* xmn = xm + (size_t)n * VV * CIN;
  for (int i = tid; i < 2 * VV * RR; i += 128) {
    const int which = (i >= VV * RR);
    const int idx = which ? i - VV * RR : i;
    const int v = idx / RR, c = idx % RR;
    const float* W = which ? W2 : W1;
    const float* b = which ? b2 : b1;
    const float* row = xmn + v * CIN;
    float s = 0.f;
    #pragma unroll
    for (int k = 0; k < CIN; ++k) s = fmaf(row[k], W[k * RR + c], s);
    s = s * (1.0f / TT) + b[c];
    if (which) m2[v][c] = s; else m1[v][c] = s;
  }
  __syncthreads();
  for (int p = tid; p < VV * VV; p += 128) {
    const int u = p / VV, v2 = p % VV;
    float r[RR];
    #pragma unroll
    for (int c = 0; c < RR; ++c) r[c] = m1[u][c] - m2[v2][c];
    float t1[HH4];
    #pragma unroll
    for (int j = 0; j < HH4; ++j) {
      float s = b4a[j];
      #pragma unroll
      for (int c = 0; c < RR; ++c) s = fmaf(r[c], W4a[c * HH4 + j], s);
      t1[j] = silu_f(s);
    }
    const float av = A[u * VV + v2];
    float hc[RR];
    #pragma unroll
    for (int c = 0; c < RR; ++c) {
      float s = b4b[c];
      #pragma unroll
      for (int j = 0; j < HH4; ++j) s = fmaf(t1[j], W4b[j * RR + c], s);
      hc[c] = silu_f(s) + av;
    }
    __half2* hp = h2 + ((size_t)n * VV * VV + p) * 5;
    hp[0] = __floats2half2_rn(hc[0], hc[1]);
    hp[1] = __floats2half2_rn(hc[2], hc[3]);
    hp[2] = __floats2half2_rn(hc[4], hc[5]);
    hp[3] = __floats2half2_rn(hc[6], hc[7]);
    hp[4] = __floats2half2_rn(hc[8], 0.f);
  }
}

// ---------------------------------------------------------------------------
// k3: per (n, t-quarter): stage x3 tile + h into LDS, agg (half2 FMA),
// a5 = silu(agg@W5a+b5a) -> LDS, then coalesced 6->64 epilogue.
// ---------------------------------------------------------------------------
__global__ __launch_bounds__(256) void k3_out(
    const __half* __restrict__ x3h, const __half2* __restrict__ h2,
    const float* __restrict__ W5a, const float* __restrict__ b5a,
    const float* __restrict__ W5b, const float* __restrict__ b5b,
    float* __restrict__ out) {
  const int bid = blockIdx.x;           // n*NT + tq
  const int n = bid >> 2, tq = bid & (NT - 1);
  const int tid = threadIdx.x;
  __shared__ __half2 x3s[VV * TQ * 6];  // [v][t][12 halves]
  __shared__ __half2 h2s[VV * VV * 5];  // [u][v][10 halves]
  __shared__ __half2 a5s[VV * TQ * 3];  // [p][6 halves]

  // stage x3 tile: 25 chunks of 192 uints (each contiguous in global)
  for (int i = tid; i < VV * 192; i += 256) {
    const int v = i / 192, rr = i - v * 192;
    const uint32* src =
        (const uint32*)(x3h + (((size_t)(n * VV + v)) * TT + tq * TQ) * 12);
    ((uint32*)x3s)[v * 192 + rr] = src[rr];
  }
  // stage h: 3125 uints contiguous
  {
    const uint32* src = (const uint32*)(h2 + (size_t)n * VV * VV * 5);
    for (int i = tid; i < VV * VV * 5; i += 256) ((uint32*)h2s)[i] = src[i];
  }
  __syncthreads();

  // C1: agg + first MLP layer -> a5 (half2) in LDS
  for (int p = tid; p < VV * TQ; p += 256) {
    const int u = p >> 5, t = p & (TQ - 1);
    __half2 a0 = __floats2half2_rn(0.f, 0.f), a1 = a0, a2 = a0, a3 = a0, a4 = a0;
    const __half2* hr = h2s + u * VV * 5;
    const __half2* xr = x3s + t * 6;
    #pragma unroll 5
    for (int v = 0; v < VV; ++v) {
      const __half2* hv = hr + v * 5;
      const __half2* xv = xr + v * TQ * 6;
      a0 = __hfma2(hv[0], xv[0], a0);
      a1 = __hfma2(hv[1], xv[1], a1);
      a2 = __hfma2(hv[2], xv[2], a2);
      a3 = __hfma2(hv[3], xv[3], a3);
      a4 = __hfma2(hv[4], xv[4], a4);
    }
    float ag[RR];
    ag[0] = __low2float(a0); ag[1] = __high2float(a0);
    ag[2] = __low2float(a1); ag[3] = __high2float(a1);
    ag[4] = __low2float(a2); ag[5] = __high2float(a2);
    ag[6] = __low2float(a3); ag[7] = __high2float(a3);
    ag[8] = __low2float(a4);
    float a5v[HH5];
    #pragma unroll
    for (int j = 0; j < HH5; ++j) {
      float s = b5a[j];
      #pragma unroll
      for (int c = 0; c < RR; ++c) s = fmaf(ag[c], W5a[c * HH5 + j], s);
      a5v[j] = silu_f(s);
    }
    a5s[p * 3 + 0] = __floats2half2_rn(a5v[0], a5v[1]);
    a5s[p * 3 + 1] = __floats2half2_rn(a5v[2], a5v[3]);
    a5s[p * 3 + 2] = __floats2half2_rn(a5v[4], a5v[5]);
  }
  __syncthreads();

  // C2: coalesced epilogue. 16 lanes per (u,t) row; lane handles 4 channels.
  const int cq = (tid & 15) * 4;
  float4 wb[HH5];
  #pragma unroll
  for (int j = 0; j < HH5; ++j) wb[j] = *(const float4*)(W5b + j * CO + cq);
  const float4 bb = *(const float4*)(b5b + cq);
  #pragma unroll 2
  for (int it = 0; it < (VV * TQ) / 16; ++it) {
    const int q = it * 16 + (tid >> 4);
    const int u = q >> 5, t = q & (TQ - 1);
    const __half2 p01 = a5s[q * 3 + 0];
    const __half2 p23 = a5s[q * 3 + 1];
    const __half2 p45 = a5s[q * 3 + 2];
    const float a0 = __low2float(p01), a1 = __high2float(p01);
    const float a2 = __low2float(p23), a3 = __high2float(p23);
    const float a4 = __low2float(p45), a5 = __high2float(p45);
    float4 y;
    y.x = silu_f(bb.x + a0 * wb[0].x + a1 * wb[1].x + a2 * wb[2].x +
                 a3 * wb[3].x + a4 * wb[4].x + a5 * wb[5].x);
    y.y = silu_f(bb.y + a0 * wb[0].y + a1 * wb[1].y + a2 * wb[2].y +
                 a3 * wb[3].y + a4 * wb[4].y + a5 * wb[5].y);
    y.z = silu_f(bb.z + a0 * wb[0].z + a1 * wb[1].z + a2 * wb[2].z +
                 a3 * wb[3].z + a4 * wb[4].z + a5 * wb[5].z);
    y.w = silu_f(bb.w + a0 * wb[0].w + a1 * wb[1].w + a2 * wb[2].w +
                 a3 * wb[3].w + a4 * wb[4].w + a5 * wb[5].w);
    float* orow = out + ((size_t)(n * VV + u) * TT + tq * TQ + t) * CO + cq;
    *(float4*)orow = y;
  }
}

extern "C" void kernel_launch(void* const* d_in, const int* in_sizes, int n_in,
                              void* d_out, int out_size, void* d_ws, size_t ws_size,
                              hipStream_t stream) {
  const float* x   = (const float*)d_in[0];
  const float* A   = (const float*)d_in[1];
  const float* W1  = (const float*)d_in[2];
  const float* b1  = (const float*)d_in[3];
  const float* W2  = (const float*)d_in[4];
  const float* b2  = (const float*)d_in[5];
  const float* W3  = (const float*)d_in[6];
  const float* b3  = (const float*)d_in[7];
  const float* W4a = (const float*)d_in[8];
  const float* b4a = (const float*)d_in[9];
  const float* W4b = (const float*)d_in[10];
  const float* b4b = (const float*)d_in[11];
  const float* W5a = (const float*)d_in[12];
  const float* b5a = (const float*)d_in[13];
  const float* W5b = (const float*)d_in[14];
  const float* b5b = (const float*)d_in[15];

  char* ws = (char*)d_ws;
  __half* x3h  = (__half*)ws;                               // 19,660,800 B
  float*  xm   = (float*)(ws + 19660800);                   //  1,638,400 B
  __half2* h2  = (__half2*)(ws + 19660800 + 1638400);       //  3,200,000 B
  float* out = (float*)d_out;

  hipLaunchKernelGGL(k1_proj, dim3(NN * VV), dim3(128), 0, stream, x, W3, b3, x3h, xm);
  hipLaunchKernelGGL(k2_h, dim3(NN), dim3(128), 0, stream,
                     xm, A, W1, b1, W2, b2, W4a, b4a, W4b, b4b, h2);
  hipLaunchKernelGGL(k3_out, dim3(NN * NT), dim3(256), 0, stream,
                     x3h, h2, W5a, b5a, W5b, b5b, out);
}